// Round 2
// baseline (460.958 us; speedup 1.0000x reference)
//
#include <hip/hip_runtime.h>

// out[i, j] = x[i, j] * w[j]
// x: 16384 x 4096 fp32, w: 4096 fp32.  Pure streaming: 256 MiB in + 256 MiB out.
// Demonstrated session ceiling (poison fills): 6.5 TB/s -> floor ~83 us.
//
// Key facts exploited:
//  - grid*block*4 elements stride = 2^21, a multiple of SIZE=4096
//    -> each thread's column (and thus its w value) is loop-invariant: hoist it.
//  - n4 = 16Mi is an exact multiple of the stride -> fixed 32-iteration loop,
//    unrolled 4x for 4 outstanding global_load_dwordx4 per thread.

#define SIZE 4096
#define SIZE_MASK (SIZE - 1)

__global__ __launch_bounds__(256) void colscale_kernel(
    const float4* __restrict__ x4,
    const float*  __restrict__ w,
    float4* __restrict__ out4,
    long long n4)
{
    const long long stride = (long long)gridDim.x * blockDim.x;
    const long long i0 = (long long)blockIdx.x * blockDim.x + threadIdx.x;

    // Column of this thread's float4; invariant iff (stride*4) % SIZE == 0.
    const int col4 = (int)((i0 << 2) & SIZE_MASK) >> 2;
    const float4 wv = ((const float4*)w)[col4];   // hoisted: one L1 load total

    if (((stride << 2) & SIZE_MASK) == 0 && (n4 % stride) == 0) {
        // Fast path: fixed trip count, loop-invariant w.
        const int iters = (int)(n4 / stride);
        #pragma unroll 4
        for (int it = 0; it < iters; ++it) {
            const long long i = i0 + (long long)it * stride;
            float4 xv = x4[i];
            float4 ov;
            ov.x = xv.x * wv.x;
            ov.y = xv.y * wv.y;
            ov.z = xv.z * wv.z;
            ov.w = xv.w * wv.w;
            out4[i] = ov;
        }
    } else {
        // Generic fallback (not taken for the benchmarked shape).
        for (long long i = i0; i < n4; i += stride) {
            int c4 = (int)((i << 2) & SIZE_MASK) >> 2;
            float4 wvi = ((const float4*)w)[c4];
            float4 xv = x4[i];
            float4 ov;
            ov.x = xv.x * wvi.x;
            ov.y = xv.y * wvi.y;
            ov.z = xv.z * wvi.z;
            ov.w = xv.w * wvi.w;
            out4[i] = ov;
        }
    }
}

extern "C" void kernel_launch(void* const* d_in, const int* in_sizes, int n_in,
                              void* d_out, int out_size, void* d_ws, size_t ws_size,
                              hipStream_t stream) {
    const float* x = (const float*)d_in[0];
    const float* w = (const float*)d_in[1];
    float* out = (float*)d_out;

    long long n  = (long long)out_size;   // 16384 * 4096 = 64Mi
    long long n4 = n >> 2;                // 16Mi float4s

    const int block = 256;
    // 2048 blocks = 256 CU x 8 blocks/CU; stride*4 elements = 2^21,
    // a multiple of SIZE -> w hoisting valid; n4 % stride == 0 -> no tail.
    long long want = (n4 + block - 1) / block;
    int grid = (int)(want < 2048 ? want : 2048);

    colscale_kernel<<<grid, block, 0, stream>>>(
        (const float4*)x, w, (float4*)out, n4);
}